// Round 4
// baseline (30.243 us; speedup 1.0000x reference)
//
#include <hip/hip_runtime.h>

// ST-BIF neuron, multi-step. Module constants (from reference):
//   V_TH = 0.5 (q_threshold), LEVEL = 16, sym = False -> T_MAX = 15, T_MIN = 0
//   PREFIRE = 0.0 -> the "pre" subtraction term is exactly 0 every step.
// Per-element recurrence over T time steps; elements independent across BF.
//
// R4 change: same as R3 (nontemporal load/store on both 64 MiB streams) but
// with native clang ext_vector_type, which __builtin_nontemporal_* accepts
// (HIP_vector_type<float,4> is a struct and was rejected).

typedef float f32x4 __attribute__((ext_vector_type(4)));

constexpr float V_TH    = 0.5f;
constexpr float T_MAXF  = 15.0f;   // level - 1
constexpr int   T_STEPS = 8;       // from setup_inputs: x is [T*B,...] with T=8

__global__ __launch_bounds__(256) void st_bif_kernel(
    const float* __restrict__ x,   // [T, BF] flattened
    float* __restrict__ out,       // [T, BF]
    int BF)                        // features per time step (multiple of 4)
{
    const int i = (blockIdx.x * blockDim.x + threadIdx.x) * 4;
    if (i >= BF) return;

    // Phase 1: issue all 8 loads back-to-back (independent addresses),
    // nontemporal (streaming) hint.
    f32x4 xt[T_STEPS];
    #pragma unroll
    for (int t = 0; t < T_STEPS; ++t) {
        const size_t base = (size_t)t * (size_t)BF + (size_t)i;
        xt[t] = __builtin_nontemporal_load(
                    reinterpret_cast<const f32x4*>(x + base));
    }

    // Phase 2: sequential neuron update (cheap VALU), nontemporal store per step.
    float v[4]  = {0.25f, 0.25f, 0.25f, 0.25f};   // 0.5*v_th + prefire*v_th
    float Tc[4] = {0.f, 0.f, 0.f, 0.f};

    #pragma unroll
    for (int t = 0; t < T_STEPS; ++t) {
        f32x4 o;
        #pragma unroll
        for (int j = 0; j < 4; ++j) {
            v[j] += xt[t][j];
            const bool pos = (v[j] >= V_TH) && (Tc[j] < T_MAXF);
            const bool neg = (v[j] < 0.0f)  && (Tc[j] > 0.0f);
            const float spike = pos ? 1.0f : (neg ? -1.0f : 0.0f);
            v[j]  -= V_TH * spike;   // pre term is 0 (PREFIRE == 0)
            Tc[j] += spike;
            o[j]   = spike * V_TH;   // output = spike * q_threshold
        }
        const size_t base = (size_t)t * (size_t)BF + (size_t)i;
        __builtin_nontemporal_store(o, reinterpret_cast<f32x4*>(out + base));
    }
}

extern "C" void kernel_launch(void* const* d_in, const int* in_sizes, int n_in,
                              void* d_out, int out_size, void* d_ws, size_t ws_size,
                              hipStream_t stream) {
    const float* x = (const float*)d_in[0];
    float* out = (float*)d_out;

    const int total = in_sizes[0];           // 16,777,216
    const int BF = total / T_STEPS;          // 2,097,152 (features per step)

    const int threads = 256;
    const int lanes = BF / 4;                // one thread per 4 features
    const int blocks = (lanes + threads - 1) / threads;  // 2048

    st_bif_kernel<<<blocks, threads, 0, stream>>>(x, out, BF);
}

// Round 5
// 26.793 us; speedup vs baseline: 1.1288x; 1.1288x over previous
//
#include <hip/hip_runtime.h>

// ST-BIF neuron, multi-step. Module constants (from reference):
//   V_TH = 0.5 (q_threshold), LEVEL = 16, sym = False -> T_MAX = 15, T_MIN = 0
//   PREFIRE = 0.0 -> the "pre" subtraction term is exactly 0 every step.
// Per-element recurrence over T time steps; elements independent across BF.
//
// R5: revert nontemporal (R4 regression: both streams are L3-resident across
// replays; nt bypassed the 256 MiB Infinity Cache and cost 3.6 us).
// New: defer all stores to a dense 8-deep burst at the end, reusing the
// consumed input registers xt[t] to hold outputs (zero extra VGPRs), so the
// write stream issues back-to-back like the read stream instead of being
// fragmented by the serial v(t) dependence chain.

typedef float f32x4 __attribute__((ext_vector_type(4)));

constexpr float V_TH    = 0.5f;
constexpr float T_MAXF  = 15.0f;   // level - 1
constexpr int   T_STEPS = 8;       // from setup_inputs: x is [T*B,...] with T=8

__global__ __launch_bounds__(256) void st_bif_kernel(
    const float* __restrict__ x,   // [T, BF] flattened
    float* __restrict__ out,       // [T, BF]
    int BF)                        // features per time step (multiple of 4)
{
    const int i = (blockIdx.x * blockDim.x + threadIdx.x) * 4;
    if (i >= BF) return;

    // Phase 1: dense 8-deep load burst (independent addresses, cached).
    f32x4 xt[T_STEPS];
    #pragma unroll
    for (int t = 0; t < T_STEPS; ++t) {
        const size_t base = (size_t)t * (size_t)BF + (size_t)i;
        xt[t] = *reinterpret_cast<const f32x4*>(x + base);
    }

    // Phase 2: sequential neuron update; overwrite xt[t] with the output.
    float v[4]  = {0.25f, 0.25f, 0.25f, 0.25f};   // 0.5*v_th + prefire*v_th
    float Tc[4] = {0.f, 0.f, 0.f, 0.f};

    #pragma unroll
    for (int t = 0; t < T_STEPS; ++t) {
        #pragma unroll
        for (int j = 0; j < 4; ++j) {
            v[j] += xt[t][j];
            const bool pos = (v[j] >= V_TH) && (Tc[j] < T_MAXF);
            const bool neg = (v[j] < 0.0f)  && (Tc[j] > 0.0f);
            const float spike = pos ? 1.0f : (neg ? -1.0f : 0.0f);
            v[j]  -= V_TH * spike;   // pre term is 0 (PREFIRE == 0)
            Tc[j] += spike;
            xt[t][j] = spike * V_TH; // output = spike * q_threshold
        }
    }

    // Phase 3: dense 8-deep store burst (cached, stays in L3 across replays).
    #pragma unroll
    for (int t = 0; t < T_STEPS; ++t) {
        const size_t base = (size_t)t * (size_t)BF + (size_t)i;
        *reinterpret_cast<f32x4*>(out + base) = xt[t];
    }
}

extern "C" void kernel_launch(void* const* d_in, const int* in_sizes, int n_in,
                              void* d_out, int out_size, void* d_ws, size_t ws_size,
                              hipStream_t stream) {
    const float* x = (const float*)d_in[0];
    float* out = (float*)d_out;

    const int total = in_sizes[0];           // 16,777,216
    const int BF = total / T_STEPS;          // 2,097,152 (features per step)

    const int threads = 256;
    const int lanes = BF / 4;                // one thread per 4 features
    const int blocks = (lanes + threads - 1) / threads;  // 2048

    st_bif_kernel<<<blocks, threads, 0, stream>>>(x, out, BF);
}